// Round 5
// baseline (1058.596 us; speedup 1.0000x reference)
//
#include <hip/hip_runtime.h>

#define B_ 2
#define S_ 2048
#define D_ 1024
#define H_ 16
#define DH_ 64

typedef unsigned short u16;
typedef short v8s __attribute__((ext_vector_type(8)));
typedef float v4f __attribute__((ext_vector_type(4)));

__device__ __forceinline__ u16 f2bf(float x) {
    unsigned int u = __float_as_uint(x);
    u += 0x7fffu + ((u >> 16) & 1u);          // RNE
    return (u16)(u >> 16);
}
__device__ __forceinline__ float bf2f(u16 u) {
    return __uint_as_float(((unsigned int)u) << 16);
}

typedef __attribute__((address_space(1))) void gvoid;
typedef __attribute__((address_space(3))) void lvoid;
#define CP16(g, l) __builtin_amdgcn_global_load_lds((gvoid*)(g), (lvoid*)(l), 16, 0, 0)

// ---------------------------------------------------------------------------
// fused fp32 -> bf16 convert for all 9 tensors (grid.y = tensor id)
// ---------------------------------------------------------------------------
__global__ __launch_bounds__(256) void cvt9(
    const float* __restrict__ s0, const float* __restrict__ s1,
    const float* __restrict__ s2, const float* __restrict__ s3,
    const float* __restrict__ s4, const float* __restrict__ s5,
    const float* __restrict__ s6, const float* __restrict__ s7,
    const float* __restrict__ s8,
    u16* __restrict__ d0, u16* __restrict__ d1, u16* __restrict__ d2,
    u16* __restrict__ d3, u16* __restrict__ d4, u16* __restrict__ d5,
    u16* __restrict__ d6, u16* __restrict__ d7, u16* __restrict__ d8,
    int nbig, int nsmall)
{
    int y = blockIdx.y;
    const float* s = y==0?s0:y==1?s1:y==2?s2:y==3?s3:y==4?s4:y==5?s5:y==6?s6:y==7?s7:s8;
    u16* d = y==0?d0:y==1?d1:y==2?d2:y==3?d3:y==4?d4:y==5?d5:y==6?d6:y==7?d7:d8;
    int n4 = (y < 4) ? nbig : nsmall;
    int i = blockIdx.x * 256 + threadIdx.x;
    if (i < n4) {
        float4 v = ((const float4*)s)[i];
        ushort4 o;
        o.x = f2bf(v.x); o.y = f2bf(v.y); o.z = f2bf(v.z); o.w = f2bf(v.w);
        ((ushort4*)d)[i] = o;
    }
}

// ---------------------------------------------------------------------------
// Fused 4-projection bf16 GEMM (grid.z = projection). C = A @ W^T + bias.
// proj 2 (V) writes per-head TRANSPOSED: VT[(b*16+h)*64+d][s].
// ---------------------------------------------------------------------------
__global__ __launch_bounds__(256, 3) void gemm_proj(
    const u16* __restrict__ A0, const u16* __restrict__ A1,
    const u16* __restrict__ A2, const u16* __restrict__ A3,
    const u16* __restrict__ W0, const u16* __restrict__ W1,
    const u16* __restrict__ W2, const u16* __restrict__ W3,
    const float* __restrict__ b0, const float* __restrict__ b1,
    const float* __restrict__ b2,
    u16* __restrict__ C0, u16* __restrict__ C1,
    u16* __restrict__ VT, u16* __restrict__ C3)
{
    const int K = D_, N = D_;
    const int proj = blockIdx.z;
    const u16* A = proj==0?A0:proj==1?A1:proj==2?A2:A3;
    const u16* W = proj==0?W0:proj==1?W1:proj==2?W2:W3;
    const float* bias = proj==0?b0:proj==1?b1:proj==2?b2:nullptr;

    __shared__ u16 As[128 * 32];
    __shared__ u16 Ws[128 * 32];
    const int tid  = threadIdx.x;
    const int wave = tid >> 6, lane = tid & 63;
    const int quad = lane >> 4, l15 = lane & 15;
    const int m0 = blockIdx.y * 128, n0 = blockIdx.x * 128;
    const int srow = lane >> 2, scol = (lane & 3) * 8;
    const int wr = wave >> 1, wc = wave & 1;

    v4f acc[4][4];
    #pragma unroll
    for (int i = 0; i < 4; ++i)
        #pragma unroll
        for (int j = 0; j < 4; ++j) acc[i][j] = (v4f){0.f, 0.f, 0.f, 0.f};

    for (int kb = 0; kb < K; kb += 32) {
        __syncthreads();
        #pragma unroll
        for (int c2 = 0; c2 < 2; ++c2) {
            int c = wave * 2 + c2;
            CP16(A + (size_t)(m0 + c * 16 + srow) * K + kb + scol, &As[c * 512]);
            CP16(W + (size_t)(n0 + c * 16 + srow) * K + kb + scol, &Ws[c * 512]);
        }
        __syncthreads();
        v8s af[4], bf[4];
        #pragma unroll
        for (int i = 0; i < 4; ++i)
            af[i] = *(const v8s*)&As[(wr * 64 + i * 16 + l15) * 32 + quad * 8];
        #pragma unroll
        for (int j = 0; j < 4; ++j)
            bf[j] = *(const v8s*)&Ws[(wc * 64 + j * 16 + l15) * 32 + quad * 8];
        #pragma unroll
        for (int i = 0; i < 4; ++i)
            #pragma unroll
            for (int j = 0; j < 4; ++j)
                acc[i][j] = __builtin_amdgcn_mfma_f32_16x16x32_bf16(af[i], bf[j], acc[i][j], 0, 0, 0);
    }

    float bb[4];
    #pragma unroll
    for (int j = 0; j < 4; ++j)
        bb[j] = bias ? bias[n0 + wc * 64 + j * 16 + l15] : 0.f;

    if (proj == 2) {
        #pragma unroll
        for (int i = 0; i < 4; ++i)
            #pragma unroll
            for (int j = 0; j < 4; ++j) {
                int r0 = m0 + wr * 64 + i * 16 + quad * 4;       // s (global row)
                int c  = n0 + wc * 64 + j * 16 + l15;            // h*64+d
                ushort4 pw;
                pw.x = f2bf(acc[i][j][0] + bb[j]);
                pw.y = f2bf(acc[i][j][1] + bb[j]);
                pw.z = f2bf(acc[i][j][2] + bb[j]);
                pw.w = f2bf(acc[i][j][3] + bb[j]);
                size_t row_vt = (size_t)((r0 >> 11) * 16 + (c >> 6)) * 64 + (c & 63);
                *(ushort4*)&VT[row_vt * S_ + (r0 & 2047)] = pw;
            }
    } else {
        u16* C = proj == 0 ? C0 : proj == 1 ? C1 : C3;
        #pragma unroll
        for (int i = 0; i < 4; ++i)
            #pragma unroll
            for (int j = 0; j < 4; ++j)
                #pragma unroll
                for (int reg = 0; reg < 4; ++reg) {
                    int r = m0 + wr * 64 + i * 16 + quad * 4 + reg;
                    int c = n0 + wc * 64 + j * 16 + l15;
                    C[(size_t)r * N + c] = f2bf(acc[i][j][reg] + bb[j]);
                }
    }
}

// ---------------------------------------------------------------------------
// Output GEMM: fp32 out, 64x128 tile.
// ---------------------------------------------------------------------------
__global__ __launch_bounds__(256, 3) void gemm_out(
    const u16* __restrict__ A, const u16* __restrict__ W,
    const float* __restrict__ bias, float* __restrict__ C)
{
    const int K = D_, N = D_;
    __shared__ u16 As[64 * 32];
    __shared__ u16 Ws[128 * 32];
    const int tid  = threadIdx.x;
    const int wave = tid >> 6, lane = tid & 63;
    const int quad = lane >> 4, l15 = lane & 15;
    const int m0 = blockIdx.y * 64, n0 = blockIdx.x * 128;
    const int srow = lane >> 2, scol = (lane & 3) * 8;
    const int wr = wave >> 1, wc = wave & 1;

    v4f acc[2][4];
    #pragma unroll
    for (int i = 0; i < 2; ++i)
        #pragma unroll
        for (int j = 0; j < 4; ++j) acc[i][j] = (v4f){0.f, 0.f, 0.f, 0.f};

    for (int kb = 0; kb < K; kb += 32) {
        __syncthreads();
        CP16(A + (size_t)(m0 + wave * 16 + srow) * K + kb + scol, &As[wave * 512]);
        CP16(W + (size_t)(n0 + wave * 16 + srow) * K + kb + scol, &Ws[wave * 512]);
        CP16(W + (size_t)(n0 + (wave + 4) * 16 + srow) * K + kb + scol, &Ws[(wave + 4) * 512]);
        __syncthreads();
        v8s af[2], bf[4];
        #pragma unroll
        for (int i = 0; i < 2; ++i)
            af[i] = *(const v8s*)&As[(wr * 32 + i * 16 + l15) * 32 + quad * 8];
        #pragma unroll
        for (int j = 0; j < 4; ++j)
            bf[j] = *(const v8s*)&Ws[(wc * 64 + j * 16 + l15) * 32 + quad * 8];
        #pragma unroll
        for (int i = 0; i < 2; ++i)
            #pragma unroll
            for (int j = 0; j < 4; ++j)
                acc[i][j] = __builtin_amdgcn_mfma_f32_16x16x32_bf16(af[i], bf[j], acc[i][j], 0, 0, 0);
    }

    #pragma unroll
    for (int i = 0; i < 2; ++i)
        #pragma unroll
        for (int j = 0; j < 4; ++j)
            #pragma unroll
            for (int reg = 0; reg < 4; ++reg) {
                int r = m0 + wr * 32 + i * 16 + quad * 4 + reg;
                int c = n0 + wc * 64 + j * 16 + l15;
                C[(size_t)r * N + c] = acc[i][j][reg] + bias[c];
            }
}

// ---------------------------------------------------------------------------
// MFMA flash relative attention, v4 — phase-specialized K-loop.
// tmin = k0-q0-31.  Realizable tmin ≡ {33,1} (mod 64), so:
//   pure1  (tmin <= -93): all gathered t <= 0, no t==1, j = S-1+tmin+rw
//   generic(-92..1)     : 1-2 steps, full branch/select logic
//   pure2  (tmin >= 2)  : all gathered t >= 2, j = tmin-2+rw
// Pure phases: single pos branch, linear window addressing, bare gather.
// ---------------------------------------------------------------------------
__global__ __launch_bounds__(256, 4) void rel_attn4(
    const u16* __restrict__ QH, const u16* __restrict__ KH,
    const u16* __restrict__ VT, const u16* __restrict__ PH,
    const float* __restrict__ ub, const float* __restrict__ vb,
    u16* __restrict__ AO)
{
    __shared__ u16 PmT[2][96][36];   // pos products, transposed [wcol][qrow]
    __shared__ u16 ps[32][72];       // probs (bf16), [qrow][kcol]
    __shared__ float sex[32][4];     // final cross-wave sum exchange

    const int tid  = threadIdx.x;
    const int wave = tid >> 6, lane = tid & 63;
    const int quad = lane >> 4, l15 = lane & 15;
    const int q0 = blockIdx.x * 32;
    const int bh = blockIdx.y, bb = bh >> 4, h = bh & 15;
    const size_t base = (size_t)bb * S_ * D_ + (size_t)h * DH_;
    const size_t vtb  = (size_t)bh * DH_ * S_;

    // ---- A-fragments for qu (=qh+u) and qv (=qh+v, rows +0/+1), in regs ----
    v8s quf[2][2], qvf0[2][2], qvf1[2][2];
    #pragma unroll
    for (int kc = 0; kc < 2; ++kc) {
        float ubv[8], vbv[8];
        #pragma unroll
        for (int j = 0; j < 8; ++j) {
            ubv[j] = ub[h * DH_ + kc * 32 + quad * 8 + j];
            vbv[j] = vb[h * DH_ + kc * 32 + quad * 8 + j];
        }
        #pragma unroll
        for (int Rp = 0; Rp < 2; ++Rp) {
            int r0 = q0 + Rp * 16 + l15;
            v8s raw0 = *(const v8s*)&QH[base + (size_t)r0 * D_ + kc * 32 + quad * 8];
            int r1 = min(r0 + 1, S_ - 1);
            v8s raw1 = *(const v8s*)&QH[base + (size_t)r1 * D_ + kc * 32 + quad * 8];
            #pragma unroll
            for (int j = 0; j < 8; ++j) {
                float f0 = bf2f((u16)raw0[j]);
                quf[Rp][kc][j]  = (short)f2bf(f0 + ubv[j]);
                qvf0[Rp][kc][j] = (short)f2bf(f0 + vbv[j]);
                qvf1[Rp][kc][j] = (short)f2bf(bf2f((u16)raw1[j]) + vbv[j]);
            }
        }
    }

    v4f o[2];
    o[0] = (v4f){0.f, 0.f, 0.f, 0.f};
    o[1] = (v4f){0.f, 0.f, 0.f, 0.f};
    float l_r[2][4];
    #pragma unroll
    for (int Rp = 0; Rp < 2; ++Rp)
        #pragma unroll
        for (int reg = 0; reg < 4; ++reg) l_r[Rp][reg] = 0.f;

    const int kcol = wave * 16 + l15;

    // one K-step; `phase` is a literal at each call site -> fully specialized
    auto body = [&](int k0, const int phase) {
        const int tmin = k0 - q0 - 31;

        // ---- K / V fragments from global ----
        v8s kbf[2], vbf[2];
        #pragma unroll
        for (int kc = 0; kc < 2; ++kc) {
            kbf[kc] = *(const v8s*)&KH[base + (size_t)(k0 + kcol) * D_ + kc * 32 + quad * 8];
            vbf[kc] = *(const v8s*)&VT[vtb + (size_t)kcol * S_ + k0 + kc * 32 + quad * 8];
        }

        // ---- content scores ----
        v4f cs[2];
        cs[0] = (v4f){0.f, 0.f, 0.f, 0.f};
        cs[1] = (v4f){0.f, 0.f, 0.f, 0.f};
        #pragma unroll
        for (int kc = 0; kc < 2; ++kc) {
            cs[0] = __builtin_amdgcn_mfma_f32_16x16x32_bf16(quf[0][kc], kbf[kc], cs[0], 0, 0, 0);
            cs[1] = __builtin_amdgcn_mfma_f32_16x16x32_bf16(quf[1][kc], kbf[kc], cs[1], 0, 0, 0);
        }

        // ---- pos pre-products (12 tiles over 4 waves) ----
        if (phase == 1) {
            const bool doA = (tmin <= 0);
            const bool doB = (tmin + 94 >= 2);
            auto posTilesG = [&](const v8s (&qvf)[2][2], int sel) {
                #pragma unroll
                for (int jt = 0; jt < 3; ++jt) {
                    int idx = wave * 3 + jt;
                    int Rp = idx / 6, wcl = idx % 6;
                    int rw = wcl * 16 + l15;
                    int t = tmin + rw;
                    int j = (t <= 0) ? (S_ - 1 + t) : max(t - 2, 0);
                    const u16* ph = &PH[base + (size_t)j * D_ + quad * 8];
                    v4f a = (v4f){0.f, 0.f, 0.f, 0.f};
                    a = __builtin_amdgcn_mfma_f32_16x16x32_bf16(qvf[Rp][0], *(const v8s*)ph, a, 0, 0, 0);
                    a = __builtin_amdgcn_mfma_f32_16x16x32_bf16(qvf[Rp][1], *(const v8s*)(ph + 32), a, 0, 0, 0);
                    ushort4 pw;
                    pw.x = f2bf(a[0]); pw.y = f2bf(a[1]); pw.z = f2bf(a[2]); pw.w = f2bf(a[3]);
                    *(ushort4*)&PmT[sel][rw][Rp * 16 + quad * 4] = pw;
                }
            };
            if (doA) posTilesG(qvf0, 0);
            if (doB) posTilesG(qvf1, 1);
        } else {
            const int jbase = (phase == 0) ? (S_ - 1 + tmin) : (tmin - 2);
            const v8s (&qvf)[2][2] = (phase == 0) ? qvf0 : qvf1;
            #pragma unroll
            for (int jt = 0; jt < 3; ++jt) {
                int idx = wave * 3 + jt;
                int Rp = idx / 6, wcl = idx % 6;
                int rw = wcl * 16 + l15;
                const u16* ph = &PH[base + (size_t)(jbase + rw) * D_ + quad * 8];
                v4f a = (v4f){0.f, 0.f, 0.f, 0.f};
                a = __builtin_amdgcn_mfma_f32_16x16x32_bf16(qvf[Rp][0], *(const v8s*)ph, a, 0, 0, 0);
                a = __builtin_amdgcn_mfma_f32_16x16x32_bf16(qvf[Rp][1], *(const v8s*)(ph + 32), a, 0, 0, 0);
                ushort4 pw;
                pw.x = f2bf(a[0]); pw.y = f2bf(a[1]); pw.z = f2bf(a[2]); pw.w = f2bf(a[3]);
                *(ushort4*)&PmT[0][rw][Rp * 16 + quad * 4] = pw;
            }
        }
        __syncthreads();   // B1: PmT visible

        // ---- gather pos, exp, accumulate row-sums, write probs ----
        #pragma unroll
        for (int Rp = 0; Rp < 2; ++Rp)
            #pragma unroll
            for (int reg = 0; reg < 4; ++reg) {
                int qrow = Rp * 16 + quad * 4 + reg;
                int wcol = kcol - qrow + 31;          // 0..94, loop-invariant
                float pos;
                if (phase == 1) {
                    int t = tmin + wcol;
                    const bool doA = (tmin <= 0), doB = (tmin + 94 >= 2);
                    int sel = doB ? (doA ? (t >= 2 ? 1 : 0) : 1) : 0;
                    pos = bf2f(PmT[sel][wcol][qrow]);
                    if (t == 1) pos = 0.f;
                } else {
                    pos = bf2f(PmT[0][wcol][qrow]);
                }
                float e = __expf((cs[Rp][reg] + pos) * 0.03125f);
                ps[qrow][kcol] = f2bf(e);
                l_r[Rp][reg] += e;
            }
        __syncthreads();   // B2: ps visible

        // ---- PV ----
        #pragma unroll
        for (int kc = 0; kc < 2; ++kc) {
            v8s af0 = *(const v8s*)&ps[l15][kc * 32 + quad * 8];
            v8s af1 = *(const v8s*)&ps[16 + l15][kc * 32 + quad * 8];
            o[0] = __builtin_amdgcn_mfma_f32_16x16x32_bf16(af0, vbf[kc], o[0], 0, 0, 0);
            o[1] = __builtin_amdgcn_mfma_f32_16x16x32_bf16(af1, vbf[kc], o[1], 0, 0, 0);
        }
    };

    // phase bounds (see header comment)
    const int k1end    = (q0 >= 62) ? ((((q0 - 62) >> 6) + 1) << 6) : 0;
    const int k2start  = min((((q0 + 96) >> 6) << 6), S_);

    int k0 = 0;
    for (; k0 < k1end; k0 += 64)   body(k0, 0);
    for (; k0 < k2start; k0 += 64) body(k0, 1);
    for (; k0 < S_; k0 += 64)      body(k0, 2);

    // ---- final row-sum reduction (once) ----
    #pragma unroll
    for (int Rp = 0; Rp < 2; ++Rp)
        #pragma unroll
        for (int reg = 0; reg < 4; ++reg) {
            float s = l_r[Rp][reg];
            #pragma unroll
            for (int off = 1; off < 16; off <<= 1)
                s += __shfl_xor(s, off, 16);
            if (l15 == 0) sex[Rp * 16 + quad * 4 + reg][wave] = s;
        }
    __syncthreads();
    #pragma unroll
    for (int Rp = 0; Rp < 2; ++Rp)
        #pragma unroll
        for (int reg = 0; reg < 4; ++reg) {
            int qrow = Rp * 16 + quad * 4 + reg;
            float4 s4 = *(const float4*)&sex[qrow][0];
            float inv = 1.f / ((s4.x + s4.y) + (s4.z + s4.w));
            AO[base + (size_t)(q0 + qrow) * D_ + kcol] = f2bf(o[Rp][reg] * inv);
        }
}

extern "C" void kernel_launch(void* const* d_in, const int* in_sizes, int n_in,
                              void* d_out, int out_size, void* d_ws, size_t ws_size,
                              hipStream_t stream)
{
    (void)in_sizes; (void)n_in; (void)out_size; (void)ws_size;
    const float* q   = (const float*)d_in[0];
    const float* k   = (const float*)d_in[1];
    const float* v   = (const float*)d_in[2];
    const float* pe  = (const float*)d_in[3];
    const float* Wq  = (const float*)d_in[4];
    const float* bq  = (const float*)d_in[5];
    const float* Wk  = (const float*)d_in[6];
    const float* bk  = (const float*)d_in[7];
    const float* Wv  = (const float*)d_in[8];
    const float* bv  = (const float*)d_in[9];
    const float* Wp  = (const float*)d_in[10];
    const float* ub  = (const float*)d_in[11];
    const float* vbs = (const float*)d_in[12];
    const float* Wo  = (const float*)d_in[13];
    const float* bo  = (const float*)d_in[14];
    float* out = (float*)d_out;

    const size_t NSD = (size_t)B_ * S_ * D_;   // 4,194,304
    const size_t DD  = (size_t)D_ * D_;
    u16* ws = (u16*)d_ws;
    u16* qB  = ws;
    u16* kB  = qB + NSD;
    u16* vB  = kB + NSD;
    u16* pB  = vB + NSD;
    u16* WqB = pB + NSD;
    u16* WkB = WqB + DD;
    u16* WvB = WkB + DD;
    u16* WpB = WvB + DD;
    u16* WoB = WpB + DD;
    u16* QH  = WoB + DD;
    u16* KH  = QH + NSD;
    u16* VT  = KH + NSD;           // V projection written transposed
    u16* PHb = VT + NSD;
    u16* AO  = qB;                 // alias: qB dead after gemm_proj

    const int M = B_ * S_;         // 4096

    cvt9<<<dim3((int)(NSD / 4 / 256), 9), 256, 0, stream>>>(
        q, k, v, pe, Wq, Wk, Wv, Wp, Wo,
        qB, kB, vB, pB, WqB, WkB, WvB, WpB, WoB,
        (int)(NSD / 4), (int)(DD / 4));

    gemm_proj<<<dim3(D_ / 128, M / 128, 4), 256, 0, stream>>>(
        qB, kB, vB, pB, WqB, WkB, WvB, WpB, bq, bk, bv, QH, KH, VT, PHb);

    rel_attn4<<<dim3(S_ / 32, B_ * H_), 256, 0, stream>>>(QH, KH, VT, PHb, ub, vbs, AO);

    gemm_out<<<dim3(D_ / 128, M / 64), 256, 0, stream>>>(AO, WoB, bo, out);
}

// Round 6
// 802.592 us; speedup vs baseline: 1.3190x; 1.3190x over previous
//
#include <hip/hip_runtime.h>

#define B_ 2
#define S_ 2048
#define D_ 1024
#define H_ 16
#define DH_ 64

typedef unsigned short u16;
typedef short v8s __attribute__((ext_vector_type(8)));
typedef float v4f __attribute__((ext_vector_type(4)));

__device__ __forceinline__ u16 f2bf(float x) {
    unsigned int u = __float_as_uint(x);
    u += 0x7fffu + ((u >> 16) & 1u);          // RNE
    return (u16)(u >> 16);
}
__device__ __forceinline__ float bf2f(u16 u) {
    return __uint_as_float(((unsigned int)u) << 16);
}

typedef __attribute__((address_space(1))) void gvoid;
typedef __attribute__((address_space(3))) void lvoid;
#define CP16(g, l) __builtin_amdgcn_global_load_lds((gvoid*)(g), (lvoid*)(l), 16, 0, 0)

// ---------------------------------------------------------------------------
// fused fp32 -> bf16 convert for all 9 tensors (grid.y = tensor id)
// ---------------------------------------------------------------------------
__global__ __launch_bounds__(256) void cvt9(
    const float* __restrict__ s0, const float* __restrict__ s1,
    const float* __restrict__ s2, const float* __restrict__ s3,
    const float* __restrict__ s4, const float* __restrict__ s5,
    const float* __restrict__ s6, const float* __restrict__ s7,
    const float* __restrict__ s8,
    u16* __restrict__ d0, u16* __restrict__ d1, u16* __restrict__ d2,
    u16* __restrict__ d3, u16* __restrict__ d4, u16* __restrict__ d5,
    u16* __restrict__ d6, u16* __restrict__ d7, u16* __restrict__ d8,
    int nbig, int nsmall)
{
    int y = blockIdx.y;
    const float* s = y==0?s0:y==1?s1:y==2?s2:y==3?s3:y==4?s4:y==5?s5:y==6?s6:y==7?s7:s8;
    u16* d = y==0?d0:y==1?d1:y==2?d2:y==3?d3:y==4?d4:y==5?d5:y==6?d6:y==7?d7:d8;
    int n4 = (y < 4) ? nbig : nsmall;
    int i = blockIdx.x * 256 + threadIdx.x;
    if (i < n4) {
        float4 v = ((const float4*)s)[i];
        ushort4 o;
        o.x = f2bf(v.x); o.y = f2bf(v.y); o.z = f2bf(v.z); o.w = f2bf(v.w);
        ((ushort4*)d)[i] = o;
    }
}

// ---------------------------------------------------------------------------
// Fused 4-projection bf16 GEMM (grid.z = projection). C = A @ W^T + bias.
// proj 2 (V) writes per-head TRANSPOSED: VT[(b*16+h)*64+d][s].
// ---------------------------------------------------------------------------
__global__ __launch_bounds__(256, 3) void gemm_proj(
    const u16* __restrict__ A0, const u16* __restrict__ A1,
    const u16* __restrict__ A2, const u16* __restrict__ A3,
    const u16* __restrict__ W0, const u16* __restrict__ W1,
    const u16* __restrict__ W2, const u16* __restrict__ W3,
    const float* __restrict__ b0, const float* __restrict__ b1,
    const float* __restrict__ b2,
    u16* __restrict__ C0, u16* __restrict__ C1,
    u16* __restrict__ VT, u16* __restrict__ C3)
{
    const int K = D_, N = D_;
    const int proj = blockIdx.z;
    const u16* A = proj==0?A0:proj==1?A1:proj==2?A2:A3;
    const u16* W = proj==0?W0:proj==1?W1:proj==2?W2:W3;
    const float* bias = proj==0?b0:proj==1?b1:proj==2?b2:nullptr;

    __shared__ u16 As[128 * 32];
    __shared__ u16 Ws[128 * 32];
    const int tid  = threadIdx.x;
    const int wave = tid >> 6, lane = tid & 63;
    const int quad = lane >> 4, l15 = lane & 15;
    const int m0 = blockIdx.y * 128, n0 = blockIdx.x * 128;
    const int srow = lane >> 2, scol = (lane & 3) * 8;
    const int wr = wave >> 1, wc = wave & 1;

    v4f acc[4][4];
    #pragma unroll
    for (int i = 0; i < 4; ++i)
        #pragma unroll
        for (int j = 0; j < 4; ++j) acc[i][j] = (v4f){0.f, 0.f, 0.f, 0.f};

    for (int kb = 0; kb < K; kb += 32) {
        __syncthreads();
        #pragma unroll
        for (int c2 = 0; c2 < 2; ++c2) {
            int c = wave * 2 + c2;
            CP16(A + (size_t)(m0 + c * 16 + srow) * K + kb + scol, &As[c * 512]);
            CP16(W + (size_t)(n0 + c * 16 + srow) * K + kb + scol, &Ws[c * 512]);
        }
        __syncthreads();
        v8s af[4], bf[4];
        #pragma unroll
        for (int i = 0; i < 4; ++i)
            af[i] = *(const v8s*)&As[(wr * 64 + i * 16 + l15) * 32 + quad * 8];
        #pragma unroll
        for (int j = 0; j < 4; ++j)
            bf[j] = *(const v8s*)&Ws[(wc * 64 + j * 16 + l15) * 32 + quad * 8];
        #pragma unroll
        for (int i = 0; i < 4; ++i)
            #pragma unroll
            for (int j = 0; j < 4; ++j)
                acc[i][j] = __builtin_amdgcn_mfma_f32_16x16x32_bf16(af[i], bf[j], acc[i][j], 0, 0, 0);
    }

    float bb[4];
    #pragma unroll
    for (int j = 0; j < 4; ++j)
        bb[j] = bias ? bias[n0 + wc * 64 + j * 16 + l15] : 0.f;

    if (proj == 2) {
        #pragma unroll
        for (int i = 0; i < 4; ++i)
            #pragma unroll
            for (int j = 0; j < 4; ++j) {
                int r0 = m0 + wr * 64 + i * 16 + quad * 4;       // s (global row)
                int c  = n0 + wc * 64 + j * 16 + l15;            // h*64+d
                ushort4 pw;
                pw.x = f2bf(acc[i][j][0] + bb[j]);
                pw.y = f2bf(acc[i][j][1] + bb[j]);
                pw.z = f2bf(acc[i][j][2] + bb[j]);
                pw.w = f2bf(acc[i][j][3] + bb[j]);
                size_t row_vt = (size_t)((r0 >> 11) * 16 + (c >> 6)) * 64 + (c & 63);
                *(ushort4*)&VT[row_vt * S_ + (r0 & 2047)] = pw;
            }
    } else {
        u16* C = proj == 0 ? C0 : proj == 1 ? C1 : C3;
        #pragma unroll
        for (int i = 0; i < 4; ++i)
            #pragma unroll
            for (int j = 0; j < 4; ++j)
                #pragma unroll
                for (int reg = 0; reg < 4; ++reg) {
                    int r = m0 + wr * 64 + i * 16 + quad * 4 + reg;
                    int c = n0 + wc * 64 + j * 16 + l15;
                    C[(size_t)r * N + c] = f2bf(acc[i][j][reg] + bb[j]);
                }
    }
}

// ---------------------------------------------------------------------------
// Output GEMM: fp32 out, 64x128 tile.
// ---------------------------------------------------------------------------
__global__ __launch_bounds__(256, 3) void gemm_out(
    const u16* __restrict__ A, const u16* __restrict__ W,
    const float* __restrict__ bias, float* __restrict__ C)
{
    const int K = D_, N = D_;
    __shared__ u16 As[64 * 32];
    __shared__ u16 Ws[128 * 32];
    const int tid  = threadIdx.x;
    const int wave = tid >> 6, lane = tid & 63;
    const int quad = lane >> 4, l15 = lane & 15;
    const int m0 = blockIdx.y * 64, n0 = blockIdx.x * 128;
    const int srow = lane >> 2, scol = (lane & 3) * 8;
    const int wr = wave >> 1, wc = wave & 1;

    v4f acc[2][4];
    #pragma unroll
    for (int i = 0; i < 2; ++i)
        #pragma unroll
        for (int j = 0; j < 4; ++j) acc[i][j] = (v4f){0.f, 0.f, 0.f, 0.f};

    for (int kb = 0; kb < K; kb += 32) {
        __syncthreads();
        CP16(A + (size_t)(m0 + wave * 16 + srow) * K + kb + scol, &As[wave * 512]);
        CP16(W + (size_t)(n0 + wave * 16 + srow) * K + kb + scol, &Ws[wave * 512]);
        CP16(W + (size_t)(n0 + (wave + 4) * 16 + srow) * K + kb + scol, &Ws[(wave + 4) * 512]);
        __syncthreads();
        v8s af[2], bf[4];
        #pragma unroll
        for (int i = 0; i < 2; ++i)
            af[i] = *(const v8s*)&As[(wr * 32 + i * 16 + l15) * 32 + quad * 8];
        #pragma unroll
        for (int j = 0; j < 4; ++j)
            bf[j] = *(const v8s*)&Ws[(wc * 64 + j * 16 + l15) * 32 + quad * 8];
        #pragma unroll
        for (int i = 0; i < 2; ++i)
            #pragma unroll
            for (int j = 0; j < 4; ++j)
                acc[i][j] = __builtin_amdgcn_mfma_f32_16x16x32_bf16(af[i], bf[j], acc[i][j], 0, 0, 0);
    }

    #pragma unroll
    for (int i = 0; i < 2; ++i)
        #pragma unroll
        for (int j = 0; j < 4; ++j)
            #pragma unroll
            for (int reg = 0; reg < 4; ++reg) {
                int r = m0 + wr * 32 + i * 16 + quad * 4 + reg;
                int c = n0 + wc * 64 + j * 16 + l15;
                C[(size_t)r * N + c] = acc[i][j][reg] + bias[c];
            }
}

// ---------------------------------------------------------------------------
// MFMA flash relative attention, v5 — TK=128, phase-specialized K-loop.
// tmin = k0-q0-31 (≡1 mod 32).  Gathered t ∈ [tmin, tmin+158].
//   pure1  (tmin <= -159): all t <= 0, j = S-1+tmin+rw     (no clamps)
//   generic              : 1-2 steps, full logic; doB always true here
//   pure2  (tmin >= 2)   : all t >= 2, j = tmin-2+rw
// 2 barriers per 128-K step (was 2 per 64-K).  launch_bounds(256,3): VGPR
// budget 170 — (256,4) caused spills (R5: WRITE_SIZE 47->292MB).
// ---------------------------------------------------------------------------
__global__ __launch_bounds__(256, 3) void rel_attn5(
    const u16* __restrict__ QH, const u16* __restrict__ KH,
    const u16* __restrict__ VT, const u16* __restrict__ PH,
    const float* __restrict__ ub, const float* __restrict__ vb,
    u16* __restrict__ AO)
{
    __shared__ u16 PmT[2][160][36];  // pos products, transposed [wcol][qrow]
    __shared__ u16 ps[32][136];      // probs (bf16), [qrow][kcol 0..127]
    __shared__ float sex[32][4];     // final cross-wave sum exchange

    const int tid  = threadIdx.x;
    const int wave = tid >> 6, lane = tid & 63;
    const int quad = lane >> 4, l15 = lane & 15;
    const int q0 = blockIdx.x * 32;
    const int bh = blockIdx.y, bb = bh >> 4, h = bh & 15;
    const size_t base = (size_t)bb * S_ * D_ + (size_t)h * DH_;
    const size_t vtb  = (size_t)bh * DH_ * S_;

    // ---- A-fragments for qu (=qh+u) and qv (=qh+v, rows +0/+1), in regs ----
    v8s quf[2][2], qvf0[2][2], qvf1[2][2];
    #pragma unroll
    for (int kc = 0; kc < 2; ++kc) {
        float ubv[8], vbv[8];
        #pragma unroll
        for (int j = 0; j < 8; ++j) {
            ubv[j] = ub[h * DH_ + kc * 32 + quad * 8 + j];
            vbv[j] = vb[h * DH_ + kc * 32 + quad * 8 + j];
        }
        #pragma unroll
        for (int Rp = 0; Rp < 2; ++Rp) {
            int r0 = q0 + Rp * 16 + l15;
            v8s raw0 = *(const v8s*)&QH[base + (size_t)r0 * D_ + kc * 32 + quad * 8];
            int r1 = min(r0 + 1, S_ - 1);
            v8s raw1 = *(const v8s*)&QH[base + (size_t)r1 * D_ + kc * 32 + quad * 8];
            #pragma unroll
            for (int j = 0; j < 8; ++j) {
                float f0 = bf2f((u16)raw0[j]);
                quf[Rp][kc][j]  = (short)f2bf(f0 + ubv[j]);
                qvf0[Rp][kc][j] = (short)f2bf(f0 + vbv[j]);
                qvf1[Rp][kc][j] = (short)f2bf(bf2f((u16)raw1[j]) + vbv[j]);
            }
        }
    }

    v4f o[2];
    o[0] = (v4f){0.f, 0.f, 0.f, 0.f};
    o[1] = (v4f){0.f, 0.f, 0.f, 0.f};
    float l_r[2][4];
    #pragma unroll
    for (int Rp = 0; Rp < 2; ++Rp)
        #pragma unroll
        for (int reg = 0; reg < 4; ++reg) l_r[Rp][reg] = 0.f;

    const int kc16 = wave * 16 + l15;    // within-64 column / d index

    // one TK=128 step; `phase` literal at each call site -> specialized
    auto body = [&](int k0, const int phase) {
        const int tmin = k0 - q0 - 31;

        // ---- pos pre-products: 20 tiles (2 Rp x 10 wcl) over 4 waves ----
        if (phase == 1) {
            const bool doA = (tmin <= 0);     // doB always true in generic
            #pragma unroll
            for (int jt = 0; jt < 5; ++jt) {
                int idx = wave * 5 + jt;
                int Rp = idx / 10, wcl = idx % 10;
                int rw = wcl * 16 + l15;
                int t = tmin + rw;
                int j2 = (t <= 0) ? (S_ - 1 + t) : max(t - 2, 0);
                const u16* ph = &PH[base + (size_t)j2 * D_ + quad * 8];
                if (doA) {
                    v4f a = (v4f){0.f, 0.f, 0.f, 0.f};
                    a = __builtin_amdgcn_mfma_f32_16x16x32_bf16(qvf0[Rp][0], *(const v8s*)ph, a, 0, 0, 0);
                    a = __builtin_amdgcn_mfma_f32_16x16x32_bf16(qvf0[Rp][1], *(const v8s*)(ph + 32), a, 0, 0, 0);
                    ushort4 pw;
                    pw.x = f2bf(a[0]); pw.y = f2bf(a[1]); pw.z = f2bf(a[2]); pw.w = f2bf(a[3]);
                    *(ushort4*)&PmT[0][rw][Rp * 16 + quad * 4] = pw;
                }
                {
                    v4f a = (v4f){0.f, 0.f, 0.f, 0.f};
                    a = __builtin_amdgcn_mfma_f32_16x16x32_bf16(qvf1[Rp][0], *(const v8s*)ph, a, 0, 0, 0);
                    a = __builtin_amdgcn_mfma_f32_16x16x32_bf16(qvf1[Rp][1], *(const v8s*)(ph + 32), a, 0, 0, 0);
                    ushort4 pw;
                    pw.x = f2bf(a[0]); pw.y = f2bf(a[1]); pw.z = f2bf(a[2]); pw.w = f2bf(a[3]);
                    *(ushort4*)&PmT[1][rw][Rp * 16 + quad * 4] = pw;
                }
            }
        } else {
            const int jbase = (phase == 0) ? (S_ - 1 + tmin) : (tmin - 2);
            #pragma unroll
            for (int jt = 0; jt < 5; ++jt) {
                int idx = wave * 5 + jt;
                int Rp = idx / 10, wcl = idx % 10;
                int rw = wcl * 16 + l15;
                const u16* ph = &PH[base + (size_t)(jbase + rw) * D_ + quad * 8];
                const v8s a0 = (phase == 0) ? qvf0[Rp][0] : qvf1[Rp][0];
                const v8s a1 = (phase == 0) ? qvf0[Rp][1] : qvf1[Rp][1];
                v4f a = (v4f){0.f, 0.f, 0.f, 0.f};
                a = __builtin_amdgcn_mfma_f32_16x16x32_bf16(a0, *(const v8s*)ph, a, 0, 0, 0);
                a = __builtin_amdgcn_mfma_f32_16x16x32_bf16(a1, *(const v8s*)(ph + 32), a, 0, 0, 0);
                ushort4 pw;
                pw.x = f2bf(a[0]); pw.y = f2bf(a[1]); pw.z = f2bf(a[2]); pw.w = f2bf(a[3]);
                *(ushort4*)&PmT[0][rw][Rp * 16 + quad * 4] = pw;
            }
        }
        __syncthreads();   // B1: PmT visible

        // ---- per 64-col half: content scores + gather/exp/ps-write ----
        #pragma unroll
        for (int half = 0; half < 2; ++half) {
            const int kcol = half * 64 + kc16;
            v8s kbf0 = *(const v8s*)&KH[base + (size_t)(k0 + kcol) * D_ + quad * 8];
            v8s kbf1 = *(const v8s*)&KH[base + (size_t)(k0 + kcol) * D_ + 32 + quad * 8];
            v4f cs[2];
            cs[0] = (v4f){0.f, 0.f, 0.f, 0.f};
            cs[1] = (v4f){0.f, 0.f, 0.f, 0.f};
            cs[0] = __builtin_amdgcn_mfma_f32_16x16x32_bf16(quf[0][0], kbf0, cs[0], 0, 0, 0);
            cs[0] = __builtin_amdgcn_mfma_f32_16x16x32_bf16(quf[0][1], kbf1, cs[0], 0, 0, 0);
            cs[1] = __builtin_amdgcn_mfma_f32_16x16x32_bf16(quf[1][0], kbf0, cs[1], 0, 0, 0);
            cs[1] = __builtin_amdgcn_mfma_f32_16x16x32_bf16(quf[1][1], kbf1, cs[1], 0, 0, 0);

            #pragma unroll
            for (int Rp = 0; Rp < 2; ++Rp)
                #pragma unroll
                for (int reg = 0; reg < 4; ++reg) {
                    int qrow = Rp * 16 + quad * 4 + reg;
                    int wcol = kcol - qrow + 31;      // 0..158, k0-invariant
                    float pos;
                    if (phase == 1) {
                        int t = tmin + wcol;
                        pos = bf2f(PmT[t >= 2 ? 1 : 0][wcol][qrow]);
                        if (t == 1) pos = 0.f;
                    } else {
                        pos = bf2f(PmT[0][wcol][qrow]);
                    }
                    float e = __expf((cs[Rp][reg] + pos) * 0.03125f);
                    ps[qrow][kcol] = f2bf(e);
                    l_r[Rp][reg] += e;
                }
        }
        __syncthreads();   // B2: ps visible

        // ---- PV: wave owns d-subtile kc16 ----
        #pragma unroll
        for (int kc = 0; kc < 4; ++kc) {
            v8s vbf = *(const v8s*)&VT[vtb + (size_t)kc16 * S_ + k0 + kc * 32 + quad * 8];
            v8s af0 = *(const v8s*)&ps[l15][kc * 32 + quad * 8];
            v8s af1 = *(const v8s*)&ps[16 + l15][kc * 32 + quad * 8];
            o[0] = __builtin_amdgcn_mfma_f32_16x16x32_bf16(af0, vbf, o[0], 0, 0, 0);
            o[1] = __builtin_amdgcn_mfma_f32_16x16x32_bf16(af1, vbf, o[1], 0, 0, 0);
        }
    };

    // phase bounds: pure1 iff k0 <= q0-127; pure2 iff k0 >= q0+33
    const int k1end   = (q0 >= 127) ? ((((q0 - 127) >> 7) + 1) << 7) : 0;
    const int k2start = min((((q0 + 160) >> 7) << 7), S_);

    int k0 = 0;
    for (; k0 < k1end; k0 += 128)   body(k0, 0);
    for (; k0 < k2start; k0 += 128) body(k0, 1);
    for (; k0 < S_; k0 += 128)      body(k0, 2);

    // ---- final row-sum reduction (once) ----
    #pragma unroll
    for (int Rp = 0; Rp < 2; ++Rp)
        #pragma unroll
        for (int reg = 0; reg < 4; ++reg) {
            float s = l_r[Rp][reg];
            #pragma unroll
            for (int off = 1; off < 16; off <<= 1)
                s += __shfl_xor(s, off, 16);
            if (l15 == 0) sex[Rp * 16 + quad * 4 + reg][wave] = s;
        }
    __syncthreads();
    #pragma unroll
    for (int Rp = 0; Rp < 2; ++Rp)
        #pragma unroll
        for (int reg = 0; reg < 4; ++reg) {
            int qrow = Rp * 16 + quad * 4 + reg;
            float4 s4 = *(const float4*)&sex[qrow][0];
            float inv = 1.f / ((s4.x + s4.y) + (s4.z + s4.w));
            AO[base + (size_t)(q0 + qrow) * D_ + kc16] = f2bf(o[Rp][reg] * inv);
        }
}

extern "C" void kernel_launch(void* const* d_in, const int* in_sizes, int n_in,
                              void* d_out, int out_size, void* d_ws, size_t ws_size,
                              hipStream_t stream)
{
    (void)in_sizes; (void)n_in; (void)out_size; (void)ws_size;
    const float* q   = (const float*)d_in[0];
    const float* k   = (const float*)d_in[1];
    const float* v   = (const float*)d_in[2];
    const float* pe  = (const float*)d_in[3];
    const float* Wq  = (const float*)d_in[4];
    const float* bq  = (const float*)d_in[5];
    const float* Wk  = (const float*)d_in[6];
    const float* bk  = (const float*)d_in[7];
    const float* Wv  = (const float*)d_in[8];
    const float* bv  = (const float*)d_in[9];
    const float* Wp  = (const float*)d_in[10];
    const float* ub  = (const float*)d_in[11];
    const float* vbs = (const float*)d_in[12];
    const float* Wo  = (const float*)d_in[13];
    const float* bo  = (const float*)d_in[14];
    float* out = (float*)d_out;

    const size_t NSD = (size_t)B_ * S_ * D_;   // 4,194,304
    const size_t DD  = (size_t)D_ * D_;
    u16* ws = (u16*)d_ws;
    u16* qB  = ws;
    u16* kB  = qB + NSD;
    u16* vB  = kB + NSD;
    u16* pB  = vB + NSD;
    u16* WqB = pB + NSD;
    u16* WkB = WqB + DD;
    u16* WvB = WkB + DD;
    u16* WpB = WvB + DD;
    u16* WoB = WpB + DD;
    u16* QH  = WoB + DD;
    u16* KH  = QH + NSD;
    u16* VT  = KH + NSD;           // V projection written transposed
    u16* PHb = VT + NSD;
    u16* AO  = qB;                 // alias: qB dead after gemm_proj

    const int M = B_ * S_;         // 4096

    cvt9<<<dim3((int)(NSD / 4 / 256), 9), 256, 0, stream>>>(
        q, k, v, pe, Wq, Wk, Wv, Wp, Wo,
        qB, kB, vB, pB, WqB, WkB, WvB, WpB, WoB,
        (int)(NSD / 4), (int)(DD / 4));

    gemm_proj<<<dim3(D_ / 128, M / 128, 4), 256, 0, stream>>>(
        qB, kB, vB, pB, WqB, WkB, WvB, WpB, bq, bk, bv, QH, KH, VT, PHb);

    rel_attn5<<<dim3(S_ / 32, B_ * H_), 256, 0, stream>>>(QH, KH, VT, PHb, ub, vbs, AO);

    gemm_out<<<dim3(D_ / 128, M / 64), 256, 0, stream>>>(AO, WoB, bo, out);
}

// Round 7
// 584.416 us; speedup vs baseline: 1.8114x; 1.3733x over previous
//
#include <hip/hip_runtime.h>

#define B_ 2
#define S_ 2048
#define D_ 1024
#define H_ 16
#define DH_ 64

typedef unsigned short u16;
typedef short v8s __attribute__((ext_vector_type(8)));
typedef float v4f __attribute__((ext_vector_type(4)));

__device__ __forceinline__ u16 f2bf(float x) {
    unsigned int u = __float_as_uint(x);
    u += 0x7fffu + ((u >> 16) & 1u);          // RNE
    return (u16)(u >> 16);
}
__device__ __forceinline__ float bf2f(u16 u) {
    return __uint_as_float(((unsigned int)u) << 16);
}

typedef __attribute__((address_space(1))) void gvoid;
typedef __attribute__((address_space(3))) void lvoid;
#define CP16(g, l) __builtin_amdgcn_global_load_lds((gvoid*)(g), (lvoid*)(l), 16, 0, 0)

// ---------------------------------------------------------------------------
// fused fp32 -> bf16 convert for all 9 tensors (grid.y = tensor id)
// ---------------------------------------------------------------------------
__global__ __launch_bounds__(256) void cvt9(
    const float* __restrict__ s0, const float* __restrict__ s1,
    const float* __restrict__ s2, const float* __restrict__ s3,
    const float* __restrict__ s4, const float* __restrict__ s5,
    const float* __restrict__ s6, const float* __restrict__ s7,
    const float* __restrict__ s8,
    u16* __restrict__ d0, u16* __restrict__ d1, u16* __restrict__ d2,
    u16* __restrict__ d3, u16* __restrict__ d4, u16* __restrict__ d5,
    u16* __restrict__ d6, u16* __restrict__ d7, u16* __restrict__ d8,
    int nbig, int nsmall)
{
    int y = blockIdx.y;
    const float* s = y==0?s0:y==1?s1:y==2?s2:y==3?s3:y==4?s4:y==5?s5:y==6?s6:y==7?s7:s8;
    u16* d = y==0?d0:y==1?d1:y==2?d2:y==3?d3:y==4?d4:y==5?d5:y==6?d6:y==7?d7:d8;
    int n4 = (y < 4) ? nbig : nsmall;
    int i = blockIdx.x * 256 + threadIdx.x;
    if (i < n4) {
        float4 v = ((const float4*)s)[i];
        ushort4 o;
        o.x = f2bf(v.x); o.y = f2bf(v.y); o.z = f2bf(v.z); o.w = f2bf(v.w);
        ((ushort4*)d)[i] = o;
    }
}

// ---------------------------------------------------------------------------
// Fused 4-projection bf16 GEMM (grid.z = projection). C = A @ W^T + bias.
// proj 2 (V) writes per-head TRANSPOSED: VT[(b*16+h)*64+d][s].
// ---------------------------------------------------------------------------
__global__ __launch_bounds__(256, 3) void gemm_proj(
    const u16* __restrict__ A0, const u16* __restrict__ A1,
    const u16* __restrict__ A2, const u16* __restrict__ A3,
    const u16* __restrict__ W0, const u16* __restrict__ W1,
    const u16* __restrict__ W2, const u16* __restrict__ W3,
    const float* __restrict__ b0, const float* __restrict__ b1,
    const float* __restrict__ b2,
    u16* __restrict__ C0, u16* __restrict__ C1,
    u16* __restrict__ VT, u16* __restrict__ C3)
{
    const int K = D_, N = D_;
    const int proj = blockIdx.z;
    const u16* A = proj==0?A0:proj==1?A1:proj==2?A2:A3;
    const u16* W = proj==0?W0:proj==1?W1:proj==2?W2:W3;
    const float* bias = proj==0?b0:proj==1?b1:proj==2?b2:nullptr;

    __shared__ u16 As[128 * 32];
    __shared__ u16 Ws[128 * 32];
    const int tid  = threadIdx.x;
    const int wave = tid >> 6, lane = tid & 63;
    const int quad = lane >> 4, l15 = lane & 15;
    const int m0 = blockIdx.y * 128, n0 = blockIdx.x * 128;
    const int srow = lane >> 2, scol = (lane & 3) * 8;
    const int wr = wave >> 1, wc = wave & 1;

    v4f acc[4][4];
    #pragma unroll
    for (int i = 0; i < 4; ++i)
        #pragma unroll
        for (int j = 0; j < 4; ++j) acc[i][j] = (v4f){0.f, 0.f, 0.f, 0.f};

    for (int kb = 0; kb < K; kb += 32) {
        __syncthreads();
        #pragma unroll
        for (int c2 = 0; c2 < 2; ++c2) {
            int c = wave * 2 + c2;
            CP16(A + (size_t)(m0 + c * 16 + srow) * K + kb + scol, &As[c * 512]);
            CP16(W + (size_t)(n0 + c * 16 + srow) * K + kb + scol, &Ws[c * 512]);
        }
        __syncthreads();
        v8s af[4], bf[4];
        #pragma unroll
        for (int i = 0; i < 4; ++i)
            af[i] = *(const v8s*)&As[(wr * 64 + i * 16 + l15) * 32 + quad * 8];
        #pragma unroll
        for (int j = 0; j < 4; ++j)
            bf[j] = *(const v8s*)&Ws[(wc * 64 + j * 16 + l15) * 32 + quad * 8];
        #pragma unroll
        for (int i = 0; i < 4; ++i)
            #pragma unroll
            for (int j = 0; j < 4; ++j)
                acc[i][j] = __builtin_amdgcn_mfma_f32_16x16x32_bf16(af[i], bf[j], acc[i][j], 0, 0, 0);
    }

    float bb[4];
    #pragma unroll
    for (int j = 0; j < 4; ++j)
        bb[j] = bias ? bias[n0 + wc * 64 + j * 16 + l15] : 0.f;

    if (proj == 2) {
        #pragma unroll
        for (int i = 0; i < 4; ++i)
            #pragma unroll
            for (int j = 0; j < 4; ++j) {
                int r0 = m0 + wr * 64 + i * 16 + quad * 4;       // s (global row)
                int c  = n0 + wc * 64 + j * 16 + l15;            // h*64+d
                ushort4 pw;
                pw.x = f2bf(acc[i][j][0] + bb[j]);
                pw.y = f2bf(acc[i][j][1] + bb[j]);
                pw.z = f2bf(acc[i][j][2] + bb[j]);
                pw.w = f2bf(acc[i][j][3] + bb[j]);
                size_t row_vt = (size_t)((r0 >> 11) * 16 + (c >> 6)) * 64 + (c & 63);
                *(ushort4*)&VT[row_vt * S_ + (r0 & 2047)] = pw;
            }
    } else {
        u16* C = proj == 0 ? C0 : proj == 1 ? C1 : C3;
        #pragma unroll
        for (int i = 0; i < 4; ++i)
            #pragma unroll
            for (int j = 0; j < 4; ++j)
                #pragma unroll
                for (int reg = 0; reg < 4; ++reg) {
                    int r = m0 + wr * 64 + i * 16 + quad * 4 + reg;
                    int c = n0 + wc * 64 + j * 16 + l15;
                    C[(size_t)r * N + c] = f2bf(acc[i][j][reg] + bb[j]);
                }
    }
}

// ---------------------------------------------------------------------------
// Output GEMM: fp32 out, 64x128 tile.
// ---------------------------------------------------------------------------
__global__ __launch_bounds__(256, 3) void gemm_out(
    const u16* __restrict__ A, const u16* __restrict__ W,
    const float* __restrict__ bias, float* __restrict__ C)
{
    const int K = D_, N = D_;
    __shared__ u16 As[64 * 32];
    __shared__ u16 Ws[128 * 32];
    const int tid  = threadIdx.x;
    const int wave = tid >> 6, lane = tid & 63;
    const int quad = lane >> 4, l15 = lane & 15;
    const int m0 = blockIdx.y * 64, n0 = blockIdx.x * 128;
    const int srow = lane >> 2, scol = (lane & 3) * 8;
    const int wr = wave >> 1, wc = wave & 1;

    v4f acc[2][4];
    #pragma unroll
    for (int i = 0; i < 2; ++i)
        #pragma unroll
        for (int j = 0; j < 4; ++j) acc[i][j] = (v4f){0.f, 0.f, 0.f, 0.f};

    for (int kb = 0; kb < K; kb += 32) {
        __syncthreads();
        CP16(A + (size_t)(m0 + wave * 16 + srow) * K + kb + scol, &As[wave * 512]);
        CP16(W + (size_t)(n0 + wave * 16 + srow) * K + kb + scol, &Ws[wave * 512]);
        CP16(W + (size_t)(n0 + (wave + 4) * 16 + srow) * K + kb + scol, &Ws[(wave + 4) * 512]);
        __syncthreads();
        v8s af[2], bf[4];
        #pragma unroll
        for (int i = 0; i < 2; ++i)
            af[i] = *(const v8s*)&As[(wr * 32 + i * 16 + l15) * 32 + quad * 8];
        #pragma unroll
        for (int j = 0; j < 4; ++j)
            bf[j] = *(const v8s*)&Ws[(wc * 64 + j * 16 + l15) * 32 + quad * 8];
        #pragma unroll
        for (int i = 0; i < 2; ++i)
            #pragma unroll
            for (int j = 0; j < 4; ++j)
                acc[i][j] = __builtin_amdgcn_mfma_f32_16x16x32_bf16(af[i], bf[j], acc[i][j], 0, 0, 0);
    }

    #pragma unroll
    for (int i = 0; i < 2; ++i)
        #pragma unroll
        for (int j = 0; j < 4; ++j)
            #pragma unroll
            for (int reg = 0; reg < 4; ++reg) {
                int r = m0 + wr * 32 + i * 16 + quad * 4 + reg;
                int c = n0 + wc * 64 + j * 16 + l15;
                C[(size_t)r * N + c] = acc[i][j][reg] + bias[c];
            }
}

// ---------------------------------------------------------------------------
// MFMA flash relative attention, v6 — BARRIER-FREE wave-private design.
// Each wave owns a private 16-row q-tile (q0 = (blkx*4+wave)*16) and private
// LDS slices; all DS dependencies are intra-wave (in-order per the DS pipe),
// so there is NO __syncthreads in the whole kernel. 4 waves/SIMD hide
// latency instead of barrier-synchronized drains.
// tmin = k0-q0-15 (≡ -15 mod 16):
//   pure1  (tmin <= -79): all t <= 0, j = S-1+tmin+rw
//   generic              : 1-2 steps, both branches (doA = tmin<=0)
//   pure2  (tmin >= 2)  : all t >= 2, j = tmin-2+rw
// ---------------------------------------------------------------------------
__global__ __launch_bounds__(256) void rel_attn6(
    const u16* __restrict__ QH, const u16* __restrict__ KH,
    const u16* __restrict__ VT, const u16* __restrict__ PH,
    const float* __restrict__ ub, const float* __restrict__ vb,
    u16* __restrict__ AO)
{
    // per-wave private slices; strides chosen for alignment:
    // PmT row 20 u16 = 40B (b64-aligned at quad*4), ps row 72 u16 = 144B (16B-aligned)
    __shared__ u16 PmT[4][2][80][20];   // [wave][sel][wcol][qrow]
    __shared__ u16 ps[4][16][72];       // [wave][qrow][kcol]

    const int tid  = threadIdx.x;
    const int wave = tid >> 6, lane = tid & 63;
    const int quad = lane >> 4, l15 = lane & 15;
    const int q0 = (blockIdx.x * 4 + wave) * 16;
    const int bh = blockIdx.y, bb = bh >> 4, h = bh & 15;
    const size_t base = (size_t)bb * S_ * D_ + (size_t)h * DH_;
    const size_t vtb  = (size_t)bh * DH_ * S_;

    // ---- Q fragments: qu = qh+u; qv rows +0 and +1 (in regs, 24 VGPRs) ----
    v8s quf[2], qvf0[2], qvf1[2];
    #pragma unroll
    for (int kc = 0; kc < 2; ++kc) {
        int r0 = q0 + l15;
        int r1 = min(r0 + 1, S_ - 1);
        v8s raw0 = *(const v8s*)&QH[base + (size_t)r0 * D_ + kc * 32 + quad * 8];
        v8s raw1 = *(const v8s*)&QH[base + (size_t)r1 * D_ + kc * 32 + quad * 8];
        #pragma unroll
        for (int j = 0; j < 8; ++j) {
            float ubj = ub[h * DH_ + kc * 32 + quad * 8 + j];
            float vbj = vb[h * DH_ + kc * 32 + quad * 8 + j];
            float f0 = bf2f((u16)raw0[j]);
            quf[kc][j]  = (short)f2bf(f0 + ubj);
            qvf0[kc][j] = (short)f2bf(f0 + vbj);
            qvf1[kc][j] = (short)f2bf(bf2f((u16)raw1[j]) + vbj);
        }
    }

    v4f o[4];
    float l_r[4];
    #pragma unroll
    for (int i = 0; i < 4; ++i) { o[i] = (v4f){0.f, 0.f, 0.f, 0.f}; l_r[i] = 0.f; }

    const int wb = l15 - quad * 4 + 15;   // wcol = ct*16 + wb - reg

    auto body = [&](int k0, const int phase) {
        const int tmin = k0 - q0 - 15;

        // ---- pos pre-products: 5 wcol-tiles, this wave only ----
        if (phase == 1) {
            const bool doA = (tmin <= 0);
            #pragma unroll
            for (int wcl = 0; wcl < 5; ++wcl) {
                int rw = wcl * 16 + l15;
                int t = tmin + rw;
                int j = (t <= 0) ? (S_ - 1 + t) : max(t - 2, 0);
                const u16* ph = &PH[base + (size_t)j * D_ + quad * 8];
                v8s phf0 = *(const v8s*)ph;
                v8s phf1 = *(const v8s*)(ph + 32);
                if (doA) {
                    v4f a = (v4f){0.f, 0.f, 0.f, 0.f};
                    a = __builtin_amdgcn_mfma_f32_16x16x32_bf16(qvf0[0], phf0, a, 0, 0, 0);
                    a = __builtin_amdgcn_mfma_f32_16x16x32_bf16(qvf0[1], phf1, a, 0, 0, 0);
                    ushort4 pw;
                    pw.x = f2bf(a[0]); pw.y = f2bf(a[1]); pw.z = f2bf(a[2]); pw.w = f2bf(a[3]);
                    *(ushort4*)&PmT[wave][0][rw][quad * 4] = pw;
                }
                v4f a = (v4f){0.f, 0.f, 0.f, 0.f};
                a = __builtin_amdgcn_mfma_f32_16x16x32_bf16(qvf1[0], phf0, a, 0, 0, 0);
                a = __builtin_amdgcn_mfma_f32_16x16x32_bf16(qvf1[1], phf1, a, 0, 0, 0);
                ushort4 pw;
                pw.x = f2bf(a[0]); pw.y = f2bf(a[1]); pw.z = f2bf(a[2]); pw.w = f2bf(a[3]);
                *(ushort4*)&PmT[wave][1][rw][quad * 4] = pw;
            }
        } else {
            const int jbase = (phase == 0) ? (S_ - 1 + tmin) : (tmin - 2);
            #pragma unroll
            for (int wcl = 0; wcl < 5; ++wcl) {
                int rw = wcl * 16 + l15;
                const u16* ph = &PH[base + (size_t)(jbase + rw) * D_ + quad * 8];
                const v8s a0 = (phase == 0) ? qvf0[0] : qvf1[0];
                const v8s a1 = (phase == 0) ? qvf0[1] : qvf1[1];
                v4f a = (v4f){0.f, 0.f, 0.f, 0.f};
                a = __builtin_amdgcn_mfma_f32_16x16x32_bf16(a0, *(const v8s*)ph, a, 0, 0, 0);
                a = __builtin_amdgcn_mfma_f32_16x16x32_bf16(a1, *(const v8s*)(ph + 32), a, 0, 0, 0);
                ushort4 pw;
                pw.x = f2bf(a[0]); pw.y = f2bf(a[1]); pw.z = f2bf(a[2]); pw.w = f2bf(a[3]);
                *(ushort4*)&PmT[wave][0][rw][quad * 4] = pw;
            }
        }
        // no barrier: DS ops within a wave execute in order

        // ---- content + gather/exp per 16-col tile ----
        #pragma unroll
        for (int ct = 0; ct < 4; ++ct) {
            const u16* kp = &KH[base + (size_t)(k0 + ct * 16 + l15) * D_ + quad * 8];
            v8s kbf0 = *(const v8s*)kp;
            v8s kbf1 = *(const v8s*)(kp + 32);
            v4f cs = (v4f){0.f, 0.f, 0.f, 0.f};
            cs = __builtin_amdgcn_mfma_f32_16x16x32_bf16(quf[0], kbf0, cs, 0, 0, 0);
            cs = __builtin_amdgcn_mfma_f32_16x16x32_bf16(quf[1], kbf1, cs, 0, 0, 0);
            #pragma unroll
            for (int reg = 0; reg < 4; ++reg) {
                int qrow = quad * 4 + reg;
                int wcol = ct * 16 + wb - reg;
                float pos;
                if (phase == 1) {
                    int t = tmin + wcol;
                    pos = bf2f(PmT[wave][t >= 2 ? 1 : 0][wcol][qrow]);
                    if (t == 1) pos = 0.f;
                } else {
                    pos = bf2f(PmT[wave][0][wcol][qrow]);
                }
                float e = __expf((cs[reg] + pos) * 0.03125f);
                ps[wave][qrow][ct * 16 + l15] = f2bf(e);
                l_r[reg] += e;
            }
        }

        // ---- PV (A-frags from ps, B-frags from VT) ----
        v8s af0 = *(const v8s*)&ps[wave][l15][quad * 8];
        v8s af1 = *(const v8s*)&ps[wave][l15][32 + quad * 8];
        #pragma unroll
        for (int dt = 0; dt < 4; ++dt) {
            const u16* vp = &VT[vtb + (size_t)(dt * 16 + l15) * S_ + k0 + quad * 8];
            v8s vbf0 = *(const v8s*)vp;
            v8s vbf1 = *(const v8s*)(vp + 32);
            o[dt] = __builtin_amdgcn_mfma_f32_16x16x32_bf16(af0, vbf0, o[dt], 0, 0, 0);
            o[dt] = __builtin_amdgcn_mfma_f32_16x16x32_bf16(af1, vbf1, o[dt], 0, 0, 0);
        }
    };

    // phase bounds: pure1 iff k0 <= q0-63; pure2 iff k0 >= q0+17
    const int k1end   = (q0 >= 63) ? ((((q0 - 63) >> 6) + 1) << 6) : 0;
    const int k2start = min((((q0 + 80) >> 6) << 6), S_);

    int k0 = 0;
    for (; k0 < k1end; k0 += 64)   body(k0, 0);
    for (; k0 < k2start; k0 += 64) body(k0, 1);
    for (; k0 < S_; k0 += 64)      body(k0, 2);

    // ---- row sums: in-quad shfl reduction (rows quad*4+reg live in this quad) ----
    #pragma unroll
    for (int reg = 0; reg < 4; ++reg) {
        float s = l_r[reg];
        #pragma unroll
        for (int off = 1; off < 16; off <<= 1)
            s += __shfl_xor(s, off, 16);
        l_r[reg] = 1.f / s;
    }
    #pragma unroll
    for (int dt = 0; dt < 4; ++dt)
        #pragma unroll
        for (int reg = 0; reg < 4; ++reg)
            AO[base + (size_t)(q0 + quad * 4 + reg) * D_ + dt * 16 + l15] =
                f2bf(o[dt][reg] * l_r[reg]);
}

extern "C" void kernel_launch(void* const* d_in, const int* in_sizes, int n_in,
                              void* d_out, int out_size, void* d_ws, size_t ws_size,
                              hipStream_t stream)
{
    (void)in_sizes; (void)n_in; (void)out_size; (void)ws_size;
    const float* q   = (const float*)d_in[0];
    const float* k   = (const float*)d_in[1];
    const float* v   = (const float*)d_in[2];
    const float* pe  = (const float*)d_in[3];
    const float* Wq  = (const float*)d_in[4];
    const float* bq  = (const float*)d_in[5];
    const float* Wk  = (const float*)d_in[6];
    const float* bk  = (const float*)d_in[7];
    const float* Wv  = (const float*)d_in[8];
    const float* bv  = (const float*)d_in[9];
    const float* Wp  = (const float*)d_in[10];
    const float* ub  = (const float*)d_in[11];
    const float* vbs = (const float*)d_in[12];
    const float* Wo  = (const float*)d_in[13];
    const float* bo  = (const float*)d_in[14];
    float* out = (float*)d_out;

    const size_t NSD = (size_t)B_ * S_ * D_;   // 4,194,304
    const size_t DD  = (size_t)D_ * D_;
    u16* ws = (u16*)d_ws;
    u16* qB  = ws;
    u16* kB  = qB + NSD;
    u16* vB  = kB + NSD;
    u16* pB  = vB + NSD;
    u16* WqB = pB + NSD;
    u16* WkB = WqB + DD;
    u16* WvB = WkB + DD;
    u16* WpB = WvB + DD;
    u16* WoB = WpB + DD;
    u16* QH  = WoB + DD;
    u16* KH  = QH + NSD;
    u16* VT  = KH + NSD;           // V projection written transposed
    u16* PHb = VT + NSD;
    u16* AO  = qB;                 // alias: qB dead after gemm_proj

    const int M = B_ * S_;         // 4096

    cvt9<<<dim3((int)(NSD / 4 / 256), 9), 256, 0, stream>>>(
        q, k, v, pe, Wq, Wk, Wv, Wp, Wo,
        qB, kB, vB, pB, WqB, WkB, WvB, WpB, WoB,
        (int)(NSD / 4), (int)(DD / 4));

    gemm_proj<<<dim3(D_ / 128, M / 128, 4), 256, 0, stream>>>(
        qB, kB, vB, pB, WqB, WkB, WvB, WpB, bq, bk, bv, QH, KH, VT, PHb);

    rel_attn6<<<dim3(S_ / 64, B_ * H_), 256, 0, stream>>>(QH, KH, VT, PHb, ub, vbs, AO);

    gemm_out<<<dim3(D_ / 128, M / 64), 256, 0, stream>>>(AO, WoB, bo, out);
}